// Round 6
// baseline (113.654 us; speedup 1.0000x reference)
//
#include <hip/hip_runtime.h>
#include <hip/hip_bf16.h>

#define N_TOTAL 8192
#define B_HALF  4096
#define D_DIM   256
#define NB      64                    // 128-row strips
#define NSLOT   64                    // partial slots per row
#define BK      32

typedef __attribute__((ext_vector_type(8))) short  short8;   // 8 x bf16
typedef __attribute__((ext_vector_type(4))) float  f32x4;

// async global->LDS, 16B per lane (dest = wave-uniform base + lane*16)
#define GLOAD16(src, dst) __builtin_amdgcn_global_load_lds( \
    (const __attribute__((address_space(1))) unsigned int*)(src), \
    (__attribute__((address_space(3))) unsigned int*)(dst), 16, 0, 0)

// ---------------------------------------------------------------------------
// Kernel 1: fused normalize + positive-pair sim.  One WAVE per pair i.
// zn rows scaled by sqrt(2) so bf16 dot = 2*cos = s directly; pos in fp32.
// ---------------------------------------------------------------------------
__global__ __launch_bounds__(256) void nrmpos_kernel(const float* __restrict__ z1,
                                                     const float* __restrict__ z2,
                                                     __hip_bfloat16* __restrict__ zn,
                                                     float* __restrict__ pos) {
    int i    = (blockIdx.x * 256 + threadIdx.x) >> 6;   // pair 0..4095
    int lane = threadIdx.x & 63;
    float4 a = reinterpret_cast<const float4*>(z1 + (size_t)i * D_DIM)[lane];
    float4 b = reinterpret_cast<const float4*>(z2 + (size_t)i * D_DIM)[lane];
    float ssa = a.x * a.x + a.y * a.y + a.z * a.z + a.w * a.w;
    float ssb = b.x * b.x + b.y * b.y + b.z * b.z + b.w * b.w;
    float dab = a.x * b.x + a.y * b.y + a.z * b.z + a.w * b.w;
#pragma unroll
    for (int m = 32; m >= 1; m >>= 1) {
        ssa += __shfl_xor(ssa, m);
        ssb += __shfl_xor(ssb, m);
        dab += __shfl_xor(dab, m);
    }
    float inva = 1.0f / fmaxf(sqrtf(ssa), 1e-8f);
    float invb = 1.0f / fmaxf(sqrtf(ssb), 1e-8f);
    float sa = 1.4142135623730951f * inva;
    float sb = 1.4142135623730951f * invb;
    ushort4 oa, ob;
    { __hip_bfloat16 t = __float2bfloat16(a.x * sa); oa.x = *reinterpret_cast<unsigned short*>(&t); }
    { __hip_bfloat16 t = __float2bfloat16(a.y * sa); oa.y = *reinterpret_cast<unsigned short*>(&t); }
    { __hip_bfloat16 t = __float2bfloat16(a.z * sa); oa.z = *reinterpret_cast<unsigned short*>(&t); }
    { __hip_bfloat16 t = __float2bfloat16(a.w * sa); oa.w = *reinterpret_cast<unsigned short*>(&t); }
    { __hip_bfloat16 t = __float2bfloat16(b.x * sb); ob.x = *reinterpret_cast<unsigned short*>(&t); }
    { __hip_bfloat16 t = __float2bfloat16(b.y * sb); ob.y = *reinterpret_cast<unsigned short*>(&t); }
    { __hip_bfloat16 t = __float2bfloat16(b.z * sb); ob.z = *reinterpret_cast<unsigned short*>(&t); }
    { __hip_bfloat16 t = __float2bfloat16(b.w * sb); ob.w = *reinterpret_cast<unsigned short*>(&t); }
    reinterpret_cast<ushort4*>(zn + (size_t)i * D_DIM)[lane]            = oa;
    reinterpret_cast<ushort4*>(zn + (size_t)(i + B_HALF) * D_DIM)[lane] = ob;
    if (lane == 0) {
        float p = 2.0f * dab * inva * invb;
        pos[i]          = p;
        pos[i + B_HALF] = p;
    }
}

// ---------------------------------------------------------------------------
// Kernel 2: SYMMETRIC fused sim+exp, 128x128 tiles, TWO tiles per block
// (one chunk of a row strip) -> 16 continuous K-steps/block (R3 amortization)
// at 4 blocks/CU (R3 co-residency).  Engine identical to proven R3/R4:
// 4 waves (2x2), 4x4 frags, BK=32, dbuf LDS via global_load_lds,
// 0-conflict XOR swizzle, one barrier per K-step.
// Block (c, bi): tiles (bi, bj0) [+ (bi, bj0+1)], bj0 = bi + 2c.
//   rowsums of strip bi  -> slot bi + c   (accumulated across both tiles)
//   colsums into strip bj -> slot bi      (per tile, parity redc buffers)
// Slots {0..bi-1} (cols) and {bi..bi+nchunk-1} (rows) are disjoint, max 63.
// Unwritten slots zeroed by hipMemsetAsync before launch.
// ---------------------------------------------------------------------------
__global__ __launch_bounds__(256, 4) void simexp_kernel(const __hip_bfloat16* __restrict__ zn,
                                                        float* __restrict__ partials) {
    __shared__ __attribute__((aligned(16))) __hip_bfloat16 lA[2][128 * BK];
    __shared__ __attribute__((aligned(16))) __hip_bfloat16 lB[2][128 * BK];
    __shared__ float redr[4][64];
    __shared__ float redc[2][4][64];

    const int c  = blockIdx.x;            // chunk within strip (0..31)
    const int bi = blockIdx.y;            // row strip (0..63)
    const int nchunk = (NB - bi + 1) >> 1;
    if (c >= nchunk) return;              // dead block
    const int bj0   = bi + 2 * c;
    const int ntile = (bj0 + 1 < NB) ? 2 : 1;
    const int NT    = ntile << 3;         // 8 or 16 K-steps

    const int tid  = threadIdx.x;
    const int lane = tid & 63;
    const int wid  = tid >> 6;
    const int wr   = wid >> 1;            // wave row 0..1
    const int wc   = wid & 1;             // wave col 0..1
    const int lrow16 = lane & 15;
    const int kgrp   = lane >> 4;
    const int pk = (kgrp ^ ((lrow16 >> 1) & 3)) * 8;   // swizzled k-chunk

    const __hip_bfloat16* Abase = zn + (size_t)bi * 128 * D_DIM;

    const int g0 = tid, g1 = tid + 256;
    const int r0 = g0 >> 2, kc0 = g0 & 3;
    const int r1 = g1 >> 2, kc1 = g1 & 3;
    const int aoff0 = r0 * D_DIM + ((kc0 ^ ((r0 >> 1) & 3)) * 8);
    const int aoff1 = r1 * D_DIM + ((kc1 ^ ((r1 >> 1) & 3)) * 8);

    auto stage = [&](int t, int buf) {
        const int ko = (t & 7) * BK;
        const __hip_bfloat16* Bb = zn + (size_t)(bj0 + (t >> 3)) * 128 * D_DIM;
        GLOAD16(Abase + aoff0 + ko, &lA[buf][g0 * 8]);
        GLOAD16(Abase + aoff1 + ko, &lA[buf][g1 * 8]);
        GLOAD16(Bb    + aoff0 + ko, &lB[buf][g0 * 8]);
        GLOAD16(Bb    + aoff1 + ko, &lB[buf][g1 * 8]);
    };

    f32x4 acc[4][4];
    float rowacc[4][4];
#pragma unroll
    for (int mt = 0; mt < 4; ++mt)
#pragma unroll
        for (int nt = 0; nt < 4; ++nt) { acc[mt][nt] = (f32x4)(0.0f); rowacc[mt][nt] = 0.0f; }

    stage(0, 0);
    __syncthreads();

    for (int t = 0; t < NT; ++t) {
        const int cur = t & 1;
        if (t + 1 < NT) stage(t + 1, cur ^ 1);

        short8 af[4], bfr[4];
#pragma unroll
        for (int mt = 0; mt < 4; ++mt)
            af[mt] = *reinterpret_cast<const short8*>(
                &lA[cur][(wr * 64 + mt * 16 + lrow16) * BK + pk]);
#pragma unroll
        for (int nt = 0; nt < 4; ++nt)
            bfr[nt] = *reinterpret_cast<const short8*>(
                &lB[cur][(wc * 64 + nt * 16 + lrow16) * BK + pk]);
#pragma unroll
        for (int mt = 0; mt < 4; ++mt)
#pragma unroll
            for (int nt = 0; nt < 4; ++nt)
                acc[mt][nt] = __builtin_amdgcn_mfma_f32_16x16x32_bf16(
                    af[mt], bfr[nt], acc[mt][nt], 0, 0, 0);

        if ((t & 7) == 7) {                // tile complete: exp-epilogue
            const int p  = t >> 3;
            const bool dg = (c == 0) && (p == 0);
            float cs[4] = {0.0f, 0.0f, 0.0f, 0.0f};
            if (dg) {
#pragma unroll
                for (int mt = 0; mt < 4; ++mt) {
                    const int lrowb = wr * 64 + mt * 16 + 4 * kgrp;
#pragma unroll
                    for (int r = 0; r < 4; ++r) {
                        const int lrow = lrowb + r;
                        float rsum = 0.0f;
#pragma unroll
                        for (int nt = 0; nt < 4; ++nt) {
                            const int lcol = wc * 64 + nt * 16 + lrow16;
                            float e = __expf(acc[mt][nt][r] - 2.0f);
                            rsum += (lrow == lcol) ? 0.0f : e;
                        }
                        rowacc[mt][r] += rsum;
                    }
                }
            } else {
#pragma unroll
                for (int mt = 0; mt < 4; ++mt)
#pragma unroll
                    for (int r = 0; r < 4; ++r) {
                        float rsum = 0.0f;
#pragma unroll
                        for (int nt = 0; nt < 4; ++nt) {
                            float e = __expf(acc[mt][nt][r] - 2.0f);
                            rsum += e;
                            cs[nt] += e;
                        }
                        rowacc[mt][r] += rsum;
                    }
#pragma unroll
                for (int nt = 0; nt < 4; ++nt) {
                    float cc = cs[nt];
                    cc += __shfl_xor(cc, 16);
                    cc += __shfl_xor(cc, 32);
                    if (kgrp == 0) redc[p][wid][nt * 16 + lrow16] = cc;
                }
            }
#pragma unroll
            for (int mt = 0; mt < 4; ++mt)
#pragma unroll
                for (int nt = 0; nt < 4; ++nt) acc[mt][nt] = (f32x4)(0.0f);
        }
        __syncthreads();                   // next-tile stage landed; buf safe
    }

    // block-end: reduce rowacc across the 16 col-lanes
#pragma unroll
    for (int mt = 0; mt < 4; ++mt)
#pragma unroll
        for (int r = 0; r < 4; ++r) {
            float v = rowacc[mt][r];
            v += __shfl_xor(v, 1); v += __shfl_xor(v, 2);
            v += __shfl_xor(v, 4); v += __shfl_xor(v, 8);
            if (lrow16 == 0) redr[wid][mt * 16 + kgrp * 4 + r] = v;
        }
    __syncthreads();

    if (tid < 128) {                       // rowsums -> slot bi + c
        const int h = tid >> 6, l = tid & 63;
        partials[(size_t)(bi + c) * N_TOTAL + bi * 128 + tid] =
            redr[h * 2][l] + redr[h * 2 + 1][l];
    } else {                               // colsums -> slot bi (per tile)
        const int ccol = tid - 128;
        const int wcc = ccol >> 6, l = ccol & 63;
        for (int p = 0; p < ntile; ++p) {
            if (c == 0 && p == 0) continue;   // diag tile: no colsum
            partials[(size_t)bi * N_TOTAL + (bj0 + p) * 128 + ccol] =
                redc[p][wcc][l] + redc[p][2 + wcc][l];
        }
    }
}

// ---------------------------------------------------------------------------
// Kernel 3: per-row lse - pos, block-partial sums (deterministic).
// ---------------------------------------------------------------------------
__global__ __launch_bounds__(256) void lse_kernel(const float* __restrict__ partials,
                                                  const float* __restrict__ pos,
                                                  float* __restrict__ bsums) {
    int tid = threadIdx.x;
    int row = blockIdx.x * 256 + tid;
    float s = 0.0f;
#pragma unroll 8
    for (int c = 0; c < NSLOT; ++c) s += partials[(size_t)c * N_TOTAL + row];
    float v = 2.0f + logf(s) - pos[row];
#pragma unroll
    for (int m = 32; m >= 1; m >>= 1) v += __shfl_xor(v, m);
    __shared__ float wsum[4];
    if ((tid & 63) == 0) wsum[tid >> 6] = v;
    __syncthreads();
    if (tid == 0) bsums[blockIdx.x] = wsum[0] + wsum[1] + wsum[2] + wsum[3];
}

__global__ void final_kernel(const float* __restrict__ bsums, float* __restrict__ out) {
    int tid = threadIdx.x;                // 64 threads
    float v = (tid < N_TOTAL / 256) ? bsums[tid] : 0.0f;
#pragma unroll
    for (int m = 32; m >= 1; m >>= 1) v += __shfl_xor(v, m);
    if (tid == 0) out[0] = v * (1.0f / (float)N_TOTAL);
}

// ---------------------------------------------------------------------------
extern "C" void kernel_launch(void* const* d_in, const int* in_sizes, int n_in,
                              void* d_out, int out_size, void* d_ws, size_t ws_size,
                              hipStream_t stream) {
    const float* z1 = (const float*)d_in[0];
    const float* z2 = (const float*)d_in[1];
    float* out = (float*)d_out;

    char* ws = (char*)d_ws;
    __hip_bfloat16* zn = (__hip_bfloat16*)ws;                              // 4 MB
    size_t off = (size_t)N_TOTAL * D_DIM * sizeof(__hip_bfloat16);
    float* pos = (float*)(ws + off);                                       // 32 KB
    off += (size_t)N_TOTAL * sizeof(float);
    float* partials = (float*)(ws + off);                                  // 2 MB
    off += (size_t)NSLOT * N_TOTAL * sizeof(float);
    float* bsums = (float*)(ws + off);                                     // 128 B

    hipMemsetAsync(partials, 0, (size_t)NSLOT * N_TOTAL * sizeof(float), stream);
    nrmpos_kernel<<<B_HALF / 4, 256, 0, stream>>>(z1, z2, zn, pos);
    simexp_kernel<<<dim3(32, NB), 256, 0, stream>>>(zn, partials);
    lse_kernel<<<N_TOTAL / 256, 256, 0, stream>>>(partials, pos, bsums);
    final_kernel<<<1, 64, 0, stream>>>(bsums, out);
}

// Round 7
// 46.440 us; speedup vs baseline: 2.4474x; 2.4474x over previous
//
#include <hip/hip_runtime.h>

#define N_TOTAL 8192
#define B_HALF  4096
#define D_DIM   256
#define BM      128
#define CSPLIT  16
#define COLS_PER_SPLIT 512
#define NTILE   4                     // 128-col B tiles per block
#define NSTEP   (NTILE * 8)           // 32 K-steps of 32

typedef __attribute__((ext_vector_type(4))) float f32x4;

// async global->LDS, 16B per lane (dest = wave-uniform base + lane*16)
#define GLOAD16(src, dst) __builtin_amdgcn_global_load_lds( \
    (const __attribute__((address_space(1))) unsigned int*)(src), \
    (__attribute__((address_space(3))) unsigned int*)(dst), 16, 0, 0)

// ---------------------------------------------------------------------------
// Kernel 1: fused normalize + positive-pair sim.  One WAVE per pair i.
// zn8 rows = fp8 e4m3 of sqrt(2)*z/||z||  (so fp8 dot = 2*cos = s directly).
// pos computed in fp32 from unrounded inputs.
// ---------------------------------------------------------------------------
__global__ __launch_bounds__(256) void nrmpos_kernel(const float* __restrict__ z1,
                                                     const float* __restrict__ z2,
                                                     unsigned char* __restrict__ zn8,
                                                     float* __restrict__ pos) {
    int i    = (blockIdx.x * 256 + threadIdx.x) >> 6;   // pair 0..4095
    int lane = threadIdx.x & 63;
    float4 a = reinterpret_cast<const float4*>(z1 + (size_t)i * D_DIM)[lane];
    float4 b = reinterpret_cast<const float4*>(z2 + (size_t)i * D_DIM)[lane];
    float ssa = a.x * a.x + a.y * a.y + a.z * a.z + a.w * a.w;
    float ssb = b.x * b.x + b.y * b.y + b.z * b.z + b.w * b.w;
    float dab = a.x * b.x + a.y * b.y + a.z * b.z + a.w * b.w;
#pragma unroll
    for (int m = 32; m >= 1; m >>= 1) {
        ssa += __shfl_xor(ssa, m);
        ssb += __shfl_xor(ssb, m);
        dab += __shfl_xor(dab, m);
    }
    float inva = 1.0f / fmaxf(sqrtf(ssa), 1e-8f);
    float invb = 1.0f / fmaxf(sqrtf(ssb), 1e-8f);
    float sa = 1.4142135623730951f * inva;
    float sb = 1.4142135623730951f * invb;
    int pa = __builtin_amdgcn_cvt_pk_fp8_f32(a.x * sa, a.y * sa, 0, false);
    pa     = __builtin_amdgcn_cvt_pk_fp8_f32(a.z * sa, a.w * sa, pa, true);
    int pb = __builtin_amdgcn_cvt_pk_fp8_f32(b.x * sb, b.y * sb, 0, false);
    pb     = __builtin_amdgcn_cvt_pk_fp8_f32(b.z * sb, b.w * sb, pb, true);
    reinterpret_cast<int*>(zn8 + (size_t)i * D_DIM)[lane]            = pa;
    reinterpret_cast<int*>(zn8 + (size_t)(i + B_HALF) * D_DIM)[lane] = pb;
    if (lane == 0) {
        float p = 2.0f * dab * inva * invb;
        pos[i]          = p;
        pos[i + B_HALF] = p;
    }
}

// ---------------------------------------------------------------------------
// Kernel 2: fused rowsum_i += sum_j exp(s_ij - 2), diag excluded.  FP8 MFMA.
// R3 engine: 4 waves (2x2), 4x4 frags, one barrier per K-step, 4 blocks/CU.
// NEW: A strip (128 x 256 fp8 = 32 KB) is LDS-RESIDENT (staged once);
// only B is double-buffered (2 x 4 KB slices) -> 4 KB/step staging vs R3's 16.
// Swizzles (both-sides, 16B-granule-expressible):
//   A: dest granule g holds source granule g^(r&15); read slot s at
//      phys s^(lrow16<<1)  -> 8 banks x 2-way (free).
//   B: dest granule h holds source h^((r>>2)&1); read kgrp at phys
//      kgrp^(((lrow16>>2)&1)<<1) -> 2-way (free).
// LDS = 32K (A) + 8K (B) = 40960 exactly -> 4 blocks/CU; reduction buffer
// aliases lB after the K-loop.
// ---------------------------------------------------------------------------
__global__ __launch_bounds__(256, 4) void simexp_kernel(const unsigned char* __restrict__ zn8,
                                                        float* __restrict__ partials) {
    __shared__ __attribute__((aligned(16))) unsigned char lA[BM * D_DIM];    // 32 KB
    __shared__ __attribute__((aligned(16))) unsigned char lB[2][BM * 32];    // 8 KB

    const int bi = blockIdx.x;            // row strip (0..63)
    const int ci = blockIdx.y;            // col split (0..15)
    const int tid  = threadIdx.x;
    const int lane = tid & 63;
    const int wid  = tid >> 6;
    const int wr   = wid >> 1;            // wave row 0..1
    const int wc   = wid & 1;             // wave col 0..1
    const int lrow16 = lane & 15;
    const int kgrp   = lane >> 4;         // 0..3
    const int xa  = lrow16 << 1;                               // A read-slot XOR
    const int pkb = (kgrp ^ (((lrow16 >> 2) & 1) << 1)) << 3;  // B read byte off

    const unsigned char* Abase = zn8 + (size_t)bi * BM * D_DIM;
    const unsigned char* Bbase = zn8 + (size_t)ci * COLS_PER_SPLIT * D_DIM;

    // --- A stage: 2048 granules of 16B, 8 per thread, source-swizzled ---
#pragma unroll
    for (int i2 = 0; i2 < 8; ++i2) {
        const int ga = tid + i2 * 256;
        const int r = ga >> 4, g = ga & 15;
        GLOAD16(Abase + r * D_DIM + ((g ^ (r & 15)) << 4), lA + (ga << 4));
    }

    // --- B stage: 256 granules per 4 KB slice, 1 per thread ---
    const int rb = tid >> 1, hb = tid & 1;
    const int boff = rb * D_DIM + ((hb ^ ((rb >> 2) & 1)) << 4);
    auto stageB = [&](int t, int buf) {
        const unsigned char* Bb = Bbase + (size_t)(t >> 3) * BM * D_DIM + ((t & 7) << 5);
        GLOAD16(Bb + boff, &lB[buf][tid << 4]);
    };

    f32x4 acc[4][4];
    float rowacc[4][4];
#pragma unroll
    for (int mt = 0; mt < 4; ++mt)
#pragma unroll
        for (int nt = 0; nt < 4; ++nt) { acc[mt][nt] = (f32x4)(0.0f); rowacc[mt][nt] = 0.0f; }

    stageB(0, 0);
    __syncthreads();                       // A + B0 staged (vmcnt drained)

    for (int t = 0; t < NSTEP; ++t) {
        const int cur = t & 1;
        if (t + 1 < NSTEP) stageB(t + 1, cur ^ 1);
        const int ks = t & 7;

        long af[4], bfr[4];
#pragma unroll
        for (int mt = 0; mt < 4; ++mt)
            af[mt] = *reinterpret_cast<const long*>(
                lA + (wr * 64 + mt * 16 + lrow16) * D_DIM
                   + (((((ks << 2) | kgrp)) ^ xa) << 3));
#pragma unroll
        for (int nt = 0; nt < 4; ++nt)
            bfr[nt] = *reinterpret_cast<const long*>(
                &lB[cur][(wc * 64 + nt * 16 + lrow16) * 32] + pkb);
#pragma unroll
        for (int mt = 0; mt < 4; ++mt)
#pragma unroll
            for (int nt = 0; nt < 4; ++nt)
                acc[mt][nt] = __builtin_amdgcn_mfma_f32_16x16x32_fp8_fp8(
                    af[mt], bfr[nt], acc[mt][nt], 0, 0, 0);

        if (ks == 7) {                     // B-tile complete: exp-epilogue
            const int p = t >> 3;
            const bool dg = (ci * NTILE + p) == bi;
            if (dg) {
#pragma unroll
                for (int mt = 0; mt < 4; ++mt) {
                    const int lrowb = wr * 64 + mt * 16 + 4 * kgrp;
#pragma unroll
                    for (int r = 0; r < 4; ++r) {
                        const int lrow = lrowb + r;
                        float s = 0.0f;
#pragma unroll
                        for (int nt = 0; nt < 4; ++nt) {
                            const int lcol = wc * 64 + nt * 16 + lrow16;
                            float e = __expf(acc[mt][nt][r] - 2.0f);
                            s += (lrow == lcol) ? 0.0f : e;
                        }
                        rowacc[mt][r] += s;
                    }
                }
            } else {
#pragma unroll
                for (int mt = 0; mt < 4; ++mt)
#pragma unroll
                    for (int r = 0; r < 4; ++r) {
                        float s = 0.0f;
#pragma unroll
                        for (int nt = 0; nt < 4; ++nt)
                            s += __expf(acc[mt][nt][r] - 2.0f);
                        rowacc[mt][r] += s;
                    }
            }
#pragma unroll
            for (int mt = 0; mt < 4; ++mt)
#pragma unroll
                for (int nt = 0; nt < 4; ++nt) acc[mt][nt] = (f32x4)(0.0f);
        }
        __syncthreads();                   // next B slice landed; buf reuse safe
    }

    // --- block-end reduce (red aliases lB: all lB reads done pre-barrier) ---
    float (*red)[64] = reinterpret_cast<float (*)[64]>(lB);
#pragma unroll
    for (int mt = 0; mt < 4; ++mt)
#pragma unroll
        for (int r = 0; r < 4; ++r) {
            float v = rowacc[mt][r];
            v += __shfl_xor(v, 1); v += __shfl_xor(v, 2);
            v += __shfl_xor(v, 4); v += __shfl_xor(v, 8);
            if (lrow16 == 0) red[wid][mt * 16 + kgrp * 4 + r] = v;
        }
    __syncthreads();
    if (tid < BM) {
        const int h = tid >> 6, l = tid & 63;
        partials[(size_t)ci * N_TOTAL + bi * BM + tid] = red[h * 2][l] + red[h * 2 + 1][l];
    }
}

// ---------------------------------------------------------------------------
// Kernel 3: per-row lse - pos, block-partial sums (deterministic).
// ---------------------------------------------------------------------------
__global__ __launch_bounds__(256) void lse_kernel(const float* __restrict__ partials,
                                                  const float* __restrict__ pos,
                                                  float* __restrict__ bsums) {
    int tid = threadIdx.x;
    int row = blockIdx.x * 256 + tid;
    float s = 0.0f;
#pragma unroll
    for (int c = 0; c < CSPLIT; ++c) s += partials[(size_t)c * N_TOTAL + row];
    float v = 2.0f + logf(s) - pos[row];
#pragma unroll
    for (int m = 32; m >= 1; m >>= 1) v += __shfl_xor(v, m);
    __shared__ float wsum[4];
    if ((tid & 63) == 0) wsum[tid >> 6] = v;
    __syncthreads();
    if (tid == 0) bsums[blockIdx.x] = wsum[0] + wsum[1] + wsum[2] + wsum[3];
}

__global__ void final_kernel(const float* __restrict__ bsums, float* __restrict__ out) {
    int tid = threadIdx.x;                // 64 threads
    float v = (tid < N_TOTAL / 256) ? bsums[tid] : 0.0f;
#pragma unroll
    for (int m = 32; m >= 1; m >>= 1) v += __shfl_xor(v, m);
    if (tid == 0) out[0] = v * (1.0f / (float)N_TOTAL);
}

// ---------------------------------------------------------------------------
extern "C" void kernel_launch(void* const* d_in, const int* in_sizes, int n_in,
                              void* d_out, int out_size, void* d_ws, size_t ws_size,
                              hipStream_t stream) {
    const float* z1 = (const float*)d_in[0];
    const float* z2 = (const float*)d_in[1];
    float* out = (float*)d_out;

    char* ws = (char*)d_ws;
    unsigned char* zn8 = (unsigned char*)ws;                               // 2 MB
    size_t off = (size_t)N_TOTAL * D_DIM;
    float* pos = (float*)(ws + off);                                       // 32 KB
    off += (size_t)N_TOTAL * sizeof(float);
    float* partials = (float*)(ws + off);                                  // 512 KB
    off += (size_t)CSPLIT * N_TOTAL * sizeof(float);
    float* bsums = (float*)(ws + off);                                     // 128 B

    nrmpos_kernel<<<B_HALF / 4, 256, 0, stream>>>(z1, z2, zn8, pos);
    simexp_kernel<<<dim3(N_TOTAL / BM, CSPLIT), 256, 0, stream>>>(zn8, partials);
    lse_kernel<<<N_TOTAL / 256, 256, 0, stream>>>(partials, pos, bsums);
    final_kernel<<<1, 64, 0, stream>>>(bsums, out);
}

// Round 8
// 40.859 us; speedup vs baseline: 2.7816x; 1.1366x over previous
//
#include <hip/hip_runtime.h>

#define N_TOTAL 8192
#define B_HALF  4096
#define D_DIM   256
#define BM      128
#define CSPLIT  8
#define COLS_PER_SPLIT 1024
#define NTILE   8                     // 128-col B tiles per block

typedef __attribute__((ext_vector_type(4))) float f32x4;
typedef __attribute__((ext_vector_type(2))) long  long2_t;   // 16 B = 2 fp8 MFMA frags

// async global->LDS, 16B per lane (dest = wave-uniform base + lane*16)
#define GLOAD16(src, dst) __builtin_amdgcn_global_load_lds( \
    (const __attribute__((address_space(1))) unsigned int*)(src), \
    (__attribute__((address_space(3))) unsigned int*)(dst), 16, 0, 0)

// ---------------------------------------------------------------------------
// Kernel 1: fused normalize + positive-pair sim.  One WAVE per pair i.
// Writes zn8 in PERMUTED-K fp8: row byte p(k) = kgrp(k)*64 + ks(k)*8 + k%8,
// where ks = k/32, kgrp = (k%32)/8.  This makes each lane's per-kgrp frags
// for all 8 K-steps contiguous (64 B) -> whole-K staging + b128 LDS reads.
// Rows scaled by sqrt(2) so fp8 dot = 2*cos = s directly.  pos in fp32.
// ---------------------------------------------------------------------------
__global__ __launch_bounds__(256) void nrmpos_kernel(const float* __restrict__ z1,
                                                     const float* __restrict__ z2,
                                                     unsigned char* __restrict__ zn8,
                                                     float* __restrict__ pos) {
    int i    = (blockIdx.x * 256 + threadIdx.x) >> 6;   // pair 0..4095
    int lane = threadIdx.x & 63;
    float4 a = reinterpret_cast<const float4*>(z1 + (size_t)i * D_DIM)[lane];
    float4 b = reinterpret_cast<const float4*>(z2 + (size_t)i * D_DIM)[lane];
    float ssa = a.x * a.x + a.y * a.y + a.z * a.z + a.w * a.w;
    float ssb = b.x * b.x + b.y * b.y + b.z * b.z + b.w * b.w;
    float dab = a.x * b.x + a.y * b.y + a.z * b.z + a.w * b.w;
#pragma unroll
    for (int m = 32; m >= 1; m >>= 1) {
        ssa += __shfl_xor(ssa, m);
        ssb += __shfl_xor(ssb, m);
        dab += __shfl_xor(dab, m);
    }
    float inva = 1.0f / fmaxf(sqrtf(ssa), 1e-8f);
    float invb = 1.0f / fmaxf(sqrtf(ssb), 1e-8f);
    float sa = 1.4142135623730951f * inva;
    float sb = 1.4142135623730951f * invb;
    int pa = __builtin_amdgcn_cvt_pk_fp8_f32(a.x * sa, a.y * sa, 0, false);
    pa     = __builtin_amdgcn_cvt_pk_fp8_f32(a.z * sa, a.w * sa, pa, true);
    int pb = __builtin_amdgcn_cvt_pk_fp8_f32(b.x * sb, b.y * sb, 0, false);
    pb     = __builtin_amdgcn_cvt_pk_fp8_f32(b.z * sb, b.w * sb, pb, true);
    // lane's 4 bytes are orig k = 4*lane..+3: ks = lane>>3, kgrp = (lane>>1)&3,
    // inner = (lane&1)*4  ->  permuted dword offset:
    int p = ((lane >> 1) & 3) * 64 + (lane >> 3) * 8 + (lane & 1) * 4;
    *reinterpret_cast<int*>(zn8 + (size_t)i * D_DIM + p)            = pa;
    *reinterpret_cast<int*>(zn8 + (size_t)(i + B_HALF) * D_DIM + p) = pb;
    if (lane == 0) {
        float pp = 2.0f * dab * inva * invb;
        pos[i]          = pp;
        pos[i + B_HALF] = pp;
    }
}

// ---------------------------------------------------------------------------
// Kernel 2: fused rowsum_i += sum_j exp(s_ij - 2), diag excluded.  FP8 MFMA.
// A strip (128x256B permuted) LDS-resident; B tile (128 cols, FULL K, 32 KB)
// single-buffered.  Per tile: 8 barrier-free K-steps (128 MFMA, b128 reads)
// -> __syncthreads -> issue next B stage -> register-only exp epilogue
// (hides load latency) -> __syncthreads (drains vmcnt).  2 barriers / tile.
// Swizzle: 16B cell c of row r stored at c^(r&15) (source-preswizzled for
// linear global_load_lds); read phys = cp ^ lrow16 -> uniform 8 lanes/bank
// cluster = b128 data-volume floor (no extra conflicts).
// Grid (64,8) = 512 blocks = exactly 2/CU, one generation. LDS 65.5 KB.
// ---------------------------------------------------------------------------
__global__ __launch_bounds__(256, 2) void simexp_kernel(const unsigned char* __restrict__ zn8,
                                                        float* __restrict__ partials) {
    __shared__ __attribute__((aligned(16))) unsigned char lA[BM * D_DIM];    // 32 KB
    __shared__ __attribute__((aligned(16))) unsigned char lB[BM * D_DIM];    // 32 KB
    __shared__ float red[4][64];                                             // 1 KB

    const int bi = blockIdx.x;            // row strip (0..63)
    const int ci = blockIdx.y;            // col split (0..7)
    const int tid  = threadIdx.x;
    const int lane = tid & 63;
    const int wid  = tid >> 6;
    const int wr   = wid >> 1;            // wave row 0..1
    const int wc   = wid & 1;             // wave col 0..1
    const int lrow16 = lane & 15;
    const int kgrp   = lane >> 4;         // 0..3

    const unsigned char* Abase  = zn8 + (size_t)bi * BM * D_DIM;
    const unsigned char* Bbase0 = zn8 + (size_t)ci * COLS_PER_SPLIT * D_DIM;

    // staging: 2048 granules of 16B per 32KB tile, 8 per thread.
    // dest granule (r, c) <- source cell c^(r&15) of row r.
    int ga[8], soff[8];
#pragma unroll
    for (int u = 0; u < 8; ++u) {
        const int g = tid + u * 256;
        const int r = g >> 4, c = g & 15;
        ga[u]   = g << 4;
        soff[u] = r * D_DIM + ((c ^ (r & 15)) << 4);
    }

    auto stageB = [&](int t) {
        const unsigned char* Bb = Bbase0 + (size_t)t * BM * D_DIM;
#pragma unroll
        for (int u = 0; u < 8; ++u) GLOAD16(Bb + soff[u], lB + ga[u]);
    };

    f32x4 acc[4][4];
    float rowacc[4][4];
#pragma unroll
    for (int mt = 0; mt < 4; ++mt)
#pragma unroll
        for (int nt = 0; nt < 4; ++nt) { acc[mt][nt] = (f32x4)(0.0f); rowacc[mt][nt] = 0.0f; }

#pragma unroll
    for (int u = 0; u < 8; ++u) GLOAD16(Abase + soff[u], lA + ga[u]);
    stageB(0);
    __syncthreads();                       // A + B0 staged (vmcnt drained)

    for (int t = 0; t < NTILE; ++t) {
        // ---- 8 K-steps, pure LDS+MFMA (no vmem, no barriers) ----
#pragma unroll
        for (int ks2 = 0; ks2 < 4; ++ks2) {            // pairs of K-steps
            const int cp = ((kgrp * 4 + ks2) ^ lrow16) << 4;   // swizzled cell
            long2_t af[4], bf[4];
#pragma unroll
            for (int mt = 0; mt < 4; ++mt)
                af[mt] = *reinterpret_cast<const long2_t*>(
                    lA + (wr * 64 + mt * 16 + lrow16) * D_DIM + cp);
#pragma unroll
            for (int nt = 0; nt < 4; ++nt)
                bf[nt] = *reinterpret_cast<const long2_t*>(
                    lB + (wc * 64 + nt * 16 + lrow16) * D_DIM + cp);
#pragma unroll
            for (int mt = 0; mt < 4; ++mt)
#pragma unroll
                for (int nt = 0; nt < 4; ++nt) {
                    acc[mt][nt] = __builtin_amdgcn_mfma_f32_16x16x32_fp8_fp8(
                        af[mt][0], bf[nt][0], acc[mt][nt], 0, 0, 0);
                    acc[mt][nt] = __builtin_amdgcn_mfma_f32_16x16x32_fp8_fp8(
                        af[mt][1], bf[nt][1], acc[mt][nt], 0, 0, 0);
                }
        }

        __syncthreads();                   // all lB reads done (cheap: vmcnt==0)
        if (t + 1 < NTILE) stageB(t + 1);  // issue next tile's loads NOW

        // ---- register-only exp epilogue (covers the staging latency) ----
        const bool dg = (ci * NTILE + t) == bi;
        if (dg) {
#pragma unroll
            for (int mt = 0; mt < 4; ++mt) {
                const int lrowb = wr * 64 + mt * 16 + 4 * kgrp;
#pragma unroll
                for (int r = 0; r < 4; ++r) {
                    const int lrow = lrowb + r;
                    float s = 0.0f;
#pragma unroll
                    for (int nt = 0; nt < 4; ++nt) {
                        const int lcol = wc * 64 + nt * 16 + lrow16;
                        float e = __expf(acc[mt][nt][r] - 2.0f);
                        s += (lrow == lcol) ? 0.0f : e;
                    }
                    rowacc[mt][r] += s;
                }
            }
        } else {
#pragma unroll
            for (int mt = 0; mt < 4; ++mt)
#pragma unroll
                for (int r = 0; r < 4; ++r) {
                    float s = 0.0f;
#pragma unroll
                    for (int nt = 0; nt < 4; ++nt)
                        s += __expf(acc[mt][nt][r] - 2.0f);
                    rowacc[mt][r] += s;
                }
        }
#pragma unroll
        for (int mt = 0; mt < 4; ++mt)
#pragma unroll
            for (int nt = 0; nt < 4; ++nt) acc[mt][nt] = (f32x4)(0.0f);

        if (t + 1 < NTILE) __syncthreads();   // drains vmcnt: B(t+1) landed
    }

    // ---- block-end reduce across the 16 col-lanes ----
#pragma unroll
    for (int mt = 0; mt < 4; ++mt)
#pragma unroll
        for (int r = 0; r < 4; ++r) {
            float v = rowacc[mt][r];
            v += __shfl_xor(v, 1); v += __shfl_xor(v, 2);
            v += __shfl_xor(v, 4); v += __shfl_xor(v, 8);
            if (lrow16 == 0) red[wid][mt * 16 + kgrp * 4 + r] = v;
        }
    __syncthreads();
    if (tid < BM) {
        const int h = tid >> 6, l = tid & 63;
        partials[(size_t)ci * N_TOTAL + bi * BM + tid] = red[h * 2][l] + red[h * 2 + 1][l];
    }
}

// ---------------------------------------------------------------------------
// Kernel 3: per-row lse - pos, block-partial sums (deterministic).
// ---------------------------------------------------------------------------
__global__ __launch_bounds__(256) void lse_kernel(const float* __restrict__ partials,
                                                  const float* __restrict__ pos,
                                                  float* __restrict__ bsums) {
    int tid = threadIdx.x;
    int row = blockIdx.x * 256 + tid;
    float s = 0.0f;
#pragma unroll
    for (int c = 0; c < CSPLIT; ++c) s += partials[(size_t)c * N_TOTAL + row];
    float v = 2.0f + logf(s) - pos[row];
#pragma unroll
    for (int m = 32; m >= 1; m >>= 1) v += __shfl_xor(v, m);
    __shared__ float wsum[4];
    if ((tid & 63) == 0) wsum[tid >> 6] = v;
    __syncthreads();
    if (tid == 0) bsums[blockIdx.x] = wsum[0] + wsum[1] + wsum[2] + wsum[3];
}

__global__ void final_kernel(const float* __restrict__ bsums, float* __restrict__ out) {
    int tid = threadIdx.x;                // 64 threads
    float v = (tid < N_TOTAL / 256) ? bsums[tid] : 0.0f;
#pragma unroll
    for (int m = 32; m >= 1; m >>= 1) v += __shfl_xor(v, m);
    if (tid == 0) out[0] = v * (1.0f / (float)N_TOTAL);
}

// ---------------------------------------------------------------------------
extern "C" void kernel_launch(void* const* d_in, const int* in_sizes, int n_in,
                              void* d_out, int out_size, void* d_ws, size_t ws_size,
                              hipStream_t stream) {
    const float* z1 = (const float*)d_in[0];
    const float* z2 = (const float*)d_in[1];
    float* out = (float*)d_out;

    char* ws = (char*)d_ws;
    unsigned char* zn8 = (unsigned char*)ws;                               // 2 MB
    size_t off = (size_t)N_TOTAL * D_DIM;
    float* pos = (float*)(ws + off);                                       // 32 KB
    off += (size_t)N_TOTAL * sizeof(float);
    float* partials = (float*)(ws + off);                                  // 256 KB
    off += (size_t)CSPLIT * N_TOTAL * sizeof(float);
    float* bsums = (float*)(ws + off);                                     // 128 B

    nrmpos_kernel<<<B_HALF / 4, 256, 0, stream>>>(z1, z2, zn8, pos);
    simexp_kernel<<<dim3(N_TOTAL / BM, CSPLIT), 256, 0, stream>>>(zn8, partials);
    lse_kernel<<<N_TOTAL / 256, 256, 0, stream>>>(partials, pos, bsums);
    final_kernel<<<1, 64, 0, stream>>>(bsums, out);
}